// Round 3
// baseline (173.157 us; speedup 1.0000x reference)
//
#include <hip/hip_runtime.h>

// ChebyshevAdditiveAngularMargin — HBM-bound elementwise op.
//   cosine = clip(outputs, -1+1e-7, 1-1e-7)
//   phi    = clenshaw(cosine, coeffs)            (Chebyshev, degree 30)
//   phi    = cosine > TH ? phi : cosine - MM
//   out    = 30 * (targets*phi + (1-targets)*cosine)   (targets one-hot)
// Traffic floor: 512 MB read + 256 MB write = 768 MB -> ~122 us @ 6.3 TB/s.
// R1 showed latency-bound (VGPR=8, 2.7 TB/s): fix with x4 unroll + batched
// independent loads (8 outstanding dwordx4/wave) + nontemporal stores.
// R2: use Clang ext_vector_type (HIP float4 class rejected by
// __builtin_nontemporal_store).

namespace {

typedef float f32x4 __attribute__((ext_vector_type(4)));

constexpr float kClipLo = -0.9999999f;   // -1 + 1e-7 rounded to f32
constexpr float kClipHi =  0.9999999f;   //  1 - 1e-7 rounded to f32
constexpr float kTH     = -0.98006657784124163f;  // cos(pi - 0.2)
constexpr float kMM     =  0.039733866159012243f; // sin(pi - 0.2) * 0.2
constexpr float kSCALE  = 30.0f;
constexpr int   kDegree = 30;            // 31 coefficients

__device__ __forceinline__ float clenshaw_phi(float x, const float* __restrict__ coeffs) {
    // b_k = c_k + 2x*b_{k+1} - b_{k+2}, k = DEGREE..0;  f(x) = b_0 - x*b_1
    const float x2 = 2.0f * x;
    float b1 = 0.0f, b2 = 0.0f;
#pragma unroll
    for (int k = kDegree; k >= 0; --k) {
        float b = coeffs[k] + x2 * b1 - b2;
        b2 = b1;
        b1 = b;
    }
    return b1 - b2 * x;
}

__device__ __forceinline__ f32x4 process4(f32x4 o, f32x4 t,
                                          const float* __restrict__ coeffs) {
    f32x4 r;
#pragma unroll
    for (int j = 0; j < 4; ++j) {
        const float x = fminf(fmaxf(o[j], kClipLo), kClipHi);
        float rv = x;  // targets == 0 path: out = cosine
        if (t[j] != 0.0f) {
            // rare path: ~1 element per 8192
            const float phi = (x > kTH) ? clenshaw_phi(x, coeffs) : (x - kMM);
            rv = t[j] * phi + (1.0f - t[j]) * x;
        }
        r[j] = kSCALE * rv;
    }
    return r;
}

__global__ __launch_bounds__(256) void cheb_aam_kernel(
    const f32x4* __restrict__ outputs4,
    const f32x4* __restrict__ targets4,
    const float* __restrict__ coeffs,
    f32x4*       __restrict__ dst4,
    int n4) {
    const int tid    = blockIdx.x * blockDim.x + threadIdx.x;
    const int stride = gridDim.x * blockDim.x;

    int i = tid;
    // Main loop: 4 float4 per thread per iteration, all loads issued before
    // any use -> 8 outstanding global_load_dwordx4 per wave.
    for (; i + 3 * stride < n4; i += 4 * stride) {
        f32x4 o0 = outputs4[i + 0 * stride];
        f32x4 o1 = outputs4[i + 1 * stride];
        f32x4 o2 = outputs4[i + 2 * stride];
        f32x4 o3 = outputs4[i + 3 * stride];
        f32x4 t0 = targets4[i + 0 * stride];
        f32x4 t1 = targets4[i + 1 * stride];
        f32x4 t2 = targets4[i + 2 * stride];
        f32x4 t3 = targets4[i + 3 * stride];

        f32x4 r0 = process4(o0, t0, coeffs);
        f32x4 r1 = process4(o1, t1, coeffs);
        f32x4 r2 = process4(o2, t2, coeffs);
        f32x4 r3 = process4(o3, t3, coeffs);

        __builtin_nontemporal_store(r0, &dst4[i + 0 * stride]);
        __builtin_nontemporal_store(r1, &dst4[i + 1 * stride]);
        __builtin_nontemporal_store(r2, &dst4[i + 2 * stride]);
        __builtin_nontemporal_store(r3, &dst4[i + 3 * stride]);
    }
    // Tail
    for (; i < n4; i += stride) {
        f32x4 r = process4(outputs4[i], targets4[i], coeffs);
        __builtin_nontemporal_store(r, &dst4[i]);
    }
}

}  // namespace

extern "C" void kernel_launch(void* const* d_in, const int* in_sizes, int n_in,
                              void* d_out, int out_size, void* d_ws, size_t ws_size,
                              hipStream_t stream) {
    const float* outputs = (const float*)d_in[0];
    const float* targets = (const float*)d_in[1];
    const float* coeffs  = (const float*)d_in[2];
    float* dst = (float*)d_out;

    const int n  = out_size;       // 8192*8192, divisible by 4
    const int n4 = n / 4;

    const int block = 256;
    int grid = (n4 + block - 1) / block;
    if (grid > 2048) grid = 2048;  // 8 blocks/CU, grid-stride the rest

    cheb_aam_kernel<<<grid, block, 0, stream>>>(
        (const f32x4*)outputs, (const f32x4*)targets, coeffs,
        (f32x4*)dst, n4);
}

// Round 4
// 145.286 us; speedup vs baseline: 1.1918x; 1.1918x over previous
//
#include <hip/hip_runtime.h>

// ChebyshevAdditiveAngularMargin — HBM/fabric-bound elementwise op.
//   cosine = clip(outputs, -1+1e-7, 1-1e-7)
//   phi    = clenshaw(cosine, coeffs)            (Chebyshev, degree 30)
//   phi    = cosine > TH ? phi : cosine - MM
//   out    = 30 * (targets*phi + (1-targets)*cosine)   (targets one-hot)
//
// Traffic floor: outputs 256MB (HBM) + targets 256MB (L3-resident, measured
// R3: FETCH==262MB) + write 256MB (HBM) -> ~120-130us at copy efficiency.
// R1 (grid-stride, no unroll): 162us. R3 (+x4 unroll +NT stores): 173us —
// NT stores reverted. R4: static exact-cover grid, one shot per thread,
// 4 coalesced float4 per array batched before use, plain stores.

namespace {

typedef float f32x4 __attribute__((ext_vector_type(4)));

constexpr float kClipLo = -0.9999999f;   // -1 + 1e-7 rounded to f32
constexpr float kClipHi =  0.9999999f;   //  1 - 1e-7 rounded to f32
constexpr float kTH     = -0.98006657784124163f;  // cos(pi - 0.2)
constexpr float kMM     =  0.039733866159012243f; // sin(pi - 0.2) * 0.2
constexpr float kSCALE  = 30.0f;
constexpr int   kDegree = 30;            // 31 coefficients
constexpr int   kPerThread = 4;          // float4s per thread per array

__device__ __forceinline__ float clenshaw_phi(float x, const float* __restrict__ coeffs) {
    // b_k = c_k + 2x*b_{k+1} - b_{k+2}, k = DEGREE..0;  f(x) = b_0 - x*b_1
    const float x2 = 2.0f * x;
    float b1 = 0.0f, b2 = 0.0f;
#pragma unroll
    for (int k = kDegree; k >= 0; --k) {
        float b = coeffs[k] + x2 * b1 - b2;
        b2 = b1;
        b1 = b;
    }
    return b1 - b2 * x;
}

__device__ __forceinline__ f32x4 process4(f32x4 o, f32x4 t,
                                          const float* __restrict__ coeffs) {
    f32x4 r;
#pragma unroll
    for (int j = 0; j < 4; ++j) {
        const float x = fminf(fmaxf(o[j], kClipLo), kClipHi);
        float rv = x;  // targets == 0 path: out = cosine
        if (t[j] != 0.0f) {
            // rare path: ~1 element per 8192
            const float phi = (x > kTH) ? clenshaw_phi(x, coeffs) : (x - kMM);
            rv = t[j] * phi + (1.0f - t[j]) * x;
        }
        r[j] = kSCALE * rv;
    }
    return r;
}

// One shot per thread: kPerThread coalesced float4 per array, stride-256
// within the block. All loads issued before any use.
__global__ __launch_bounds__(256) void cheb_aam_kernel(
    const f32x4* __restrict__ outputs4,
    const f32x4* __restrict__ targets4,
    const float* __restrict__ coeffs,
    f32x4*       __restrict__ dst4,
    int n4) {
    const int base = blockIdx.x * (256 * kPerThread) + threadIdx.x;

    if (base + 256 * (kPerThread - 1) < n4) {  // uniform fast path
        f32x4 o[kPerThread], t[kPerThread];
#pragma unroll
        for (int u = 0; u < kPerThread; ++u) o[u] = outputs4[base + 256 * u];
#pragma unroll
        for (int u = 0; u < kPerThread; ++u) t[u] = targets4[base + 256 * u];
#pragma unroll
        for (int u = 0; u < kPerThread; ++u) {
            dst4[base + 256 * u] = process4(o[u], t[u], coeffs);
        }
    } else {  // tail block (not taken for 8192x8192)
#pragma unroll
        for (int u = 0; u < kPerThread; ++u) {
            const int i = base + 256 * u;
            if (i < n4) dst4[i] = process4(outputs4[i], targets4[i], coeffs);
        }
    }
}

}  // namespace

extern "C" void kernel_launch(void* const* d_in, const int* in_sizes, int n_in,
                              void* d_out, int out_size, void* d_ws, size_t ws_size,
                              hipStream_t stream) {
    const float* outputs = (const float*)d_in[0];
    const float* targets = (const float*)d_in[1];
    const float* coeffs  = (const float*)d_in[2];
    float* dst = (float*)d_out;

    const int n  = out_size;       // 8192*8192, divisible by 4
    const int n4 = n / 4;

    const int block = 256;
    const int perBlock = block * kPerThread;           // 1024 float4 / block
    const int grid = (n4 + perBlock - 1) / perBlock;   // 16384 for 8192^2

    cheb_aam_kernel<<<grid, block, 0, stream>>>(
        (const f32x4*)outputs, (const f32x4*)targets, coeffs,
        (f32x4*)dst, n4);
}